// Round 7
// baseline (72.954 us; speedup 1.0000x reference)
//
#include <hip/hip_runtime.h>
#include <hip/hip_bf16.h>

#define M_ROWS 8192
#define HALF_N 4096
#define D 128
#define NPANEL 64        // 8192 / 128 panels
#define NTC 4            // j-tiles per chunk block
#define NBLK 544         // sum_{pi} ceil((64-pi)/4)
#define E2C 2.8853900817779268f   // INV_T(=2) * log2(e)

typedef __attribute__((ext_vector_type(4))) float f32x4;
typedef __attribute__((ext_vector_type(8))) short bf16x8;
typedef unsigned int u32;
typedef __attribute__((ext_vector_type(4))) u32 u32x4;

// ---------------------------------------------------------------------------
// Kernel A: L2-normalize rows (fp32 in, bf16 out), zero rowsum accumulator.
// ---------------------------------------------------------------------------
__global__ __launch_bounds__(256) void k_normalize(
    const float* __restrict__ zi, const float* __restrict__ zj,
    __hip_bfloat16* __restrict__ zb, float* __restrict__ rowsum)
{
    int t = blockIdx.x * 256 + threadIdx.x;
    if (t < M_ROWS) rowsum[t] = 0.0f;   // re-init every launch (ws not re-poisoned)

    int row  = t >> 6;
    int lane = t & 63;
    const float* src = (row < HALF_N) ? (zi + (size_t)row * D)
                                      : (zj + (size_t)(row - HALF_N) * D);
    float2 v = *(const float2*)(src + lane * 2);
    float ss = v.x * v.x + v.y * v.y;
    #pragma unroll
    for (int o = 32; o >= 1; o >>= 1) ss += __shfl_xor(ss, o);
    float scale = 1.0f / fmaxf(sqrtf(ss), 1e-12f);

    __hip_bfloat162 o2;
    o2.x = __float2bfloat16(v.x * scale);
    o2.y = __float2bfloat16(v.y * scale);
    *(__hip_bfloat162*)(zb + (size_t)row * D + lane * 2) = o2;
}

// ---------------------------------------------------------------------------
// Kernel B (symmetric, no LDS, no barriers): block covers row panel pi x up
// to 4 col panels pj in upper triangle; each sim tile computed once.
// A fragments in registers; B fragments read DIRECTLY from global (the 32KB
// tile is L1-resident: all 4 waves of the block stream the same tile).
// Row-side sums accumulate in registers -> 128 atomics at block end.
// Col-side sums shfl-reduced and stored non-atomically to private scratch
// colpart[pj][col][pi*4+wv]; k_rowloss folds them in.
// ---------------------------------------------------------------------------
__global__ __launch_bounds__(256) void k_simsum(
    const __hip_bfloat16* __restrict__ zb, float* __restrict__ rowsum,
    float* __restrict__ colpart)
{
    // Flattened upper-triangle chunk index -> (pi, chunk)
    int b = blockIdx.x, pi = 0;
    for (;;) { int cnt = (67 - pi) >> 2; if (b < cnt) break; b -= cnt; ++pi; }
    const int j0     = pi + (b << 2);
    const int ntiles = min(NTC, NPANEL - j0);

    const int ibase = pi * 128;
    const int tid   = threadIdx.x;
    const int wv    = tid >> 6, lane = tid & 63;
    const int lr    = lane & 15, lg = lane >> 4;
    const int rbase = wv * 32;

    // A fragments: 32 rows x K=128 per wave, in 32 VGPRs (from L2).
    bf16x8 a[2][4];
    #pragma unroll
    for (int m = 0; m < 2; ++m)
        #pragma unroll
        for (int ks = 0; ks < 4; ++ks) {
            int row = ibase + rbase + m * 16 + lr;
            a[m][ks] = *(const bf16x8*)(zb + (size_t)row * D + (ks * 4 + lg) * 8);
        }

    float eacc[2][4] = {{0.f, 0.f, 0.f, 0.f}, {0.f, 0.f, 0.f, 0.f}};

    for (int t = 0; t < ntiles; ++t) {
        const int pj = j0 + t;
        const __hip_bfloat16* bb = zb + (size_t)pj * 128 * D;

        f32x4 acc[2][8];
        #pragma unroll
        for (int m = 0; m < 2; ++m)
            #pragma unroll
            for (int n = 0; n < 8; ++n) acc[m][n] = (f32x4){0.f, 0.f, 0.f, 0.f};

        #pragma unroll
        for (int ks = 0; ks < 4; ++ks) {
            #pragma unroll
            for (int n = 0; n < 8; ++n) {
                // B fragment straight from global/L1 (no LDS).
                bf16x8 bfr = *(const bf16x8*)(bb + (size_t)(n * 16 + lr) * D + (ks * 4 + lg) * 8);
                acc[0][n] = __builtin_amdgcn_mfma_f32_16x16x32_bf16(a[0][ks], bfr, acc[0][n], 0, 0, 0);
                acc[1][n] = __builtin_amdgcn_mfma_f32_16x16x32_bf16(a[1][ks], bfr, acc[1][n], 0, 0, 0);
            }
        }

        // exp once per element; feed row accumulator AND column partials.
        float cs[8] = {0.f, 0.f, 0.f, 0.f, 0.f, 0.f, 0.f, 0.f};
        #pragma unroll
        for (int m = 0; m < 2; ++m)
            #pragma unroll
            for (int n = 0; n < 8; ++n)
                #pragma unroll
                for (int r = 0; r < 4; ++r) {
                    float e = exp2f(acc[m][n][r] * E2C);
                    eacc[m][r] += e;
                    cs[n]      += e;
                }

        // Column partials: sum over lg -> col sums for this wave's 32 rows;
        // fire-and-forget store to private scratch (no atomics, no barrier).
        if (pj != pi) {
            #pragma unroll
            for (int n = 0; n < 8; ++n) {
                cs[n] += __shfl_xor(cs[n], 16);
                cs[n] += __shfl_xor(cs[n], 32);
            }
            if (lg == 0) {
                float* dst = colpart + (size_t)pj * 32768 + (pi * 4 + wv);
                #pragma unroll
                for (int n = 0; n < 8; ++n)
                    dst[(n * 16 + lr) * 256] = cs[n];
            }
        }
    }

    // Row epilogue: reduce over the 16 col-lanes, fire-and-forget atomics.
    #pragma unroll
    for (int m = 0; m < 2; ++m)
        #pragma unroll
        for (int r = 0; r < 4; ++r) {
            float e = eacc[m][r];
            e += __shfl_xor(e, 1);
            e += __shfl_xor(e, 2);
            e += __shfl_xor(e, 4);
            e += __shfl_xor(e, 8);
            if (lr == 0)
                atomicAdd(&rowsum[ibase + rbase + m * 16 + lg * 4 + r], e);
        }
}

// ---------------------------------------------------------------------------
// Kernel C: per row, fold in column-side partials (colpart[pj][col][k],
// k = pi*4+wv < 4*pj), recompute self/pair dots,
// lse = log(total - exp(2*self) + exp(2*pos)), write lse - pos.
// ---------------------------------------------------------------------------
__global__ __launch_bounds__(256) void k_rowloss(
    const __hip_bfloat16* __restrict__ zb, const float* __restrict__ rowsum,
    const float* __restrict__ colpart, float* __restrict__ rowloss)
{
    int t = blockIdx.x * 256 + threadIdx.x;
    int row = t >> 6, lane = t & 63;
    int pair = row ^ HALF_N;
    int pj = row >> 7, cl = row & 127;

    // Column-side contributions for this row: 4*pj consecutive floats.
    const float* cp = colpart + (size_t)pj * 32768 + cl * 256;
    float colc = 0.f;
    for (int k = lane; k < 4 * pj; k += 64) colc += cp[k];

    __hip_bfloat162 av = *(const __hip_bfloat162*)(zb + (size_t)row  * D + lane * 2);
    __hip_bfloat162 bv = *(const __hip_bfloat162*)(zb + (size_t)pair * D + lane * 2);
    float ax = __bfloat162float(av.x), ay = __bfloat162float(av.y);
    float bx = __bfloat162float(bv.x), by = __bfloat162float(bv.y);
    float sd = ax * ax + ay * ay;
    float pd = ax * bx + ay * by;
    #pragma unroll
    for (int o = 32; o >= 1; o >>= 1) {
        sd   += __shfl_xor(sd, o);
        pd   += __shfl_xor(pd, o);
        colc += __shfl_xor(colc, o);
    }
    if (lane == 0) {
        float rs  = rowsum[row] + colc;
        float val = rs - exp2f(sd * E2C) + exp2f(pd * E2C);
        rowloss[row] = logf(val) - 2.0f * pd;
    }
}

// ---------------------------------------------------------------------------
// Kernel D: single-block tree reduction of rowloss[8192] -> mean.
// ---------------------------------------------------------------------------
__global__ __launch_bounds__(1024) void k_reduce(
    const float* __restrict__ rowloss, float* __restrict__ out)
{
    __shared__ float sm[16];
    int tid = threadIdx.x;
    float s = 0.f;
    #pragma unroll
    for (int i = 0; i < M_ROWS / 1024; ++i) s += rowloss[i * 1024 + tid];
    #pragma unroll
    for (int o = 32; o >= 1; o >>= 1) s += __shfl_xor(s, o);
    if ((tid & 63) == 0) sm[tid >> 6] = s;
    __syncthreads();
    if (tid == 0) {
        float tot = 0.f;
        #pragma unroll
        for (int w = 0; w < 16; ++w) tot += sm[w];
        out[0] = tot * (1.0f / (float)M_ROWS);
    }
}

// ---------------------------------------------------------------------------
extern "C" void kernel_launch(void* const* d_in, const int* in_sizes, int n_in,
                              void* d_out, int out_size, void* d_ws, size_t ws_size,
                              hipStream_t stream)
{
    const float* zi = (const float*)d_in[0];
    const float* zj = (const float*)d_in[1];

    float* rowsum  = (float*)d_ws;                               // 8192 f32
    float* rowloss = rowsum + M_ROWS;                            // 8192 f32
    __hip_bfloat16* zb = (__hip_bfloat16*)((char*)d_ws + 65536); // 8192x128 bf16
    float* colpart = (float*)((char*)d_ws + 65536 + M_ROWS * D * 2); // 64*128*256 f32 = 8 MB

    k_normalize<<<dim3(M_ROWS * 64 / 256), 256, 0, stream>>>(zi, zj, zb, rowsum);
    k_simsum<<<dim3(NBLK), dim3(256), 0, stream>>>(zb, rowsum, colpart);
    k_rowloss<<<dim3(M_ROWS * 64 / 256), 256, 0, stream>>>(zb, rowsum, colpart, rowloss);
    k_reduce<<<dim3(1), dim3(1024), 0, stream>>>(rowloss, (float*)d_out);
}

// Round 8
// 45.048 us; speedup vs baseline: 1.6195x; 1.6195x over previous
//
#include <hip/hip_runtime.h>
#include <hip/hip_bf16.h>

#define M_ROWS 8192
#define HALF_N 4096
#define D 128
#define NT 8             // tiles (128 cols) per block
#define NCHUNK 8         // 8192 / (NT*128)
#define E2C 2.8853900817779268f   // INV_T(=2) * log2(e)

typedef __attribute__((ext_vector_type(4))) float f32x4;
typedef __attribute__((ext_vector_type(8))) short bf16x8;
typedef unsigned int u32;
typedef __attribute__((ext_vector_type(4))) u32 u32x4;

// ---------------------------------------------------------------------------
// Kernel A: L2-normalize rows (fp32 in, bf16 out).
// One wave (64 lanes) per row; lane handles 2 of the 128 elements.
// ---------------------------------------------------------------------------
__global__ __launch_bounds__(256) void k_normalize(
    const float* __restrict__ zi, const float* __restrict__ zj,
    __hip_bfloat16* __restrict__ zb)
{
    int t = blockIdx.x * 256 + threadIdx.x;
    int row  = t >> 6;
    int lane = t & 63;
    const float* src = (row < HALF_N) ? (zi + (size_t)row * D)
                                      : (zj + (size_t)(row - HALF_N) * D);
    float2 v = *(const float2*)(src + lane * 2);
    float ss = v.x * v.x + v.y * v.y;
    #pragma unroll
    for (int o = 32; o >= 1; o >>= 1) ss += __shfl_xor(ss, o);
    float scale = 1.0f / fmaxf(sqrtf(ss), 1e-12f);

    __hip_bfloat162 o2;
    o2.x = __float2bfloat16(v.x * scale);
    o2.y = __float2bfloat16(v.y * scale);
    *(__hip_bfloat162*)(zb + (size_t)row * D + lane * 2) = o2;
}

// ---------------------------------------------------------------------------
// Kernel B: block (chunk, pi) computes sim rows [pi*128, +128) x cols
// [chunk*1024, +1024) — 8 tiles of 128x128. Full matrix (no symmetry; the
// delivery overhead of the symmetric scheme measured worse than 2x FLOPs).
// A-tile in registers; B-tiles double-buffered in LDS (reg-staged: linear
// coalesced loads 2 tiles ahead, swizzled ds_write 1 tile ahead), ONE
// barrier per tile. Row-side exp sums accumulate in registers across all 8
// tiles; shfl-reduce then PLAIN store to rspart[chunk][row] (no atomics —
// each (row, chunk) owned by exactly one block).
// ---------------------------------------------------------------------------
__global__ __launch_bounds__(256, 2) void k_simsum(
    const __hip_bfloat16* __restrict__ zb, float* __restrict__ rspart)
{
    __shared__ char sB[2][32768];

    const int chunk = blockIdx.x;            // 0..7
    const int pi    = blockIdx.y;            // 0..63
    const int ibase = pi * 128;
    const int jbase = chunk * (NT * 128);
    const int tid   = threadIdx.x;
    const int wv    = tid >> 6, lane = tid & 63;
    const int lr    = lane & 15, lg = lane >> 4;
    const int rbase = wv * 32;

    // A fragments: 32 rows x K=128 per wave, in 32 VGPRs (from L2).
    bf16x8 a[2][4];
    #pragma unroll
    for (int m = 0; m < 2; ++m)
        #pragma unroll
        for (int ks = 0; ks < 4; ++ks) {
            int row = ibase + rbase + m * 16 + lr;
            a[m][ks] = *(const bf16x8*)(zb + (size_t)row * D + (ks * 4 + lg) * 8);
        }

    // Reg-staged B tile: linear coalesced loads, swizzled ds_write.
    u32x4 breg[8];
    auto load_tile = [&](int t) {
        const __hip_bfloat16* src = zb + (size_t)(jbase + t * 128) * D;
        #pragma unroll
        for (int i = 0; i < 8; ++i) {
            int row = (wv * 8 + i) * 4 + lg;
            breg[i] = *(const u32x4*)(src + (size_t)row * D + lr * 8);
        }
    };
    auto write_tile = [&](char* buf) {
        #pragma unroll
        for (int i = 0; i < 8; ++i) {
            int row = (wv * 8 + i) * 4 + lg;
            *(u32x4*)(buf + row * 256 + ((lr ^ (row & 7)) << 4)) = breg[i];
        }
    };

    float eacc[2][4] = {{0.f, 0.f, 0.f, 0.f}, {0.f, 0.f, 0.f, 0.f}};

    load_tile(0);
    write_tile(sB[0]);
    load_tile(1);
    __syncthreads();

    for (int t = 0; t < NT; ++t) {
        // buf[(t+1)&1]'s last readers finished at barrier t-1 -> safe to fill.
        if (t + 1 < NT) write_tile(sB[(t + 1) & 1]);
        if (t + 2 < NT) load_tile(t + 2);

        const char* cur = sB[t & 1];
        f32x4 acc[2][8];
        #pragma unroll
        for (int m = 0; m < 2; ++m)
            #pragma unroll
            for (int n = 0; n < 8; ++n) acc[m][n] = (f32x4){0.f, 0.f, 0.f, 0.f};

        #pragma unroll
        for (int ks = 0; ks < 4; ++ks) {
            #pragma unroll
            for (int n = 0; n < 8; ++n) {
                int rowB = n * 16 + lr;
                bf16x8 bfr = *(const bf16x8*)(cur + rowB * 256 +
                              ((((ks << 2) + lg) ^ (lr & 7)) << 4));
                acc[0][n] = __builtin_amdgcn_mfma_f32_16x16x32_bf16(a[0][ks], bfr, acc[0][n], 0, 0, 0);
                acc[1][n] = __builtin_amdgcn_mfma_f32_16x16x32_bf16(a[1][ks], bfr, acc[1][n], 0, 0, 0);
            }
        }

        #pragma unroll
        for (int m = 0; m < 2; ++m)
            #pragma unroll
            for (int n = 0; n < 8; ++n)
                #pragma unroll
                for (int r = 0; r < 4; ++r)
                    eacc[m][r] += exp2f(acc[m][n][r] * E2C);

        __syncthreads();   // cur reads done; buf[(t+1)&1] writes visible
    }

    // Epilogue: reduce over the 16 col-lanes; plain store (block owns slot).
    #pragma unroll
    for (int m = 0; m < 2; ++m)
        #pragma unroll
        for (int r = 0; r < 4; ++r) {
            float e = eacc[m][r];
            e += __shfl_xor(e, 1);
            e += __shfl_xor(e, 2);
            e += __shfl_xor(e, 4);
            e += __shfl_xor(e, 8);
            if (lr == 0)
                rspart[chunk * M_ROWS + ibase + rbase + m * 16 + lg * 4 + r] = e;
        }
}

// ---------------------------------------------------------------------------
// Kernel C: per row, sum the 8 chunk partials, recompute self/pair dots
// (fp32 from bf16), lse = log(total - exp(2*self) + exp(2*pos)),
// write lse - pos. One wave per row; no atomics.
// ---------------------------------------------------------------------------
__global__ __launch_bounds__(256) void k_rowloss(
    const __hip_bfloat16* __restrict__ zb, const float* __restrict__ rspart,
    float* __restrict__ rowloss)
{
    int t = blockIdx.x * 256 + threadIdx.x;
    int row = t >> 6, lane = t & 63;
    int pair = row ^ HALF_N;

    float rs = (lane < NCHUNK) ? rspart[lane * M_ROWS + row] : 0.f;

    __hip_bfloat162 av = *(const __hip_bfloat162*)(zb + (size_t)row  * D + lane * 2);
    __hip_bfloat162 bv = *(const __hip_bfloat162*)(zb + (size_t)pair * D + lane * 2);
    float ax = __bfloat162float(av.x), ay = __bfloat162float(av.y);
    float bx = __bfloat162float(bv.x), by = __bfloat162float(bv.y);
    float sd = ax * ax + ay * ay;
    float pd = ax * bx + ay * by;
    #pragma unroll
    for (int o = 32; o >= 1; o >>= 1) {
        sd += __shfl_xor(sd, o);
        pd += __shfl_xor(pd, o);
        rs += __shfl_xor(rs, o);
    }
    if (lane == 0) {
        float val = rs - exp2f(sd * E2C) + exp2f(pd * E2C);
        rowloss[row] = logf(val) - 2.0f * pd;
    }
}

// ---------------------------------------------------------------------------
// Kernel D: single-block tree reduction of rowloss[8192] -> mean.
// ---------------------------------------------------------------------------
__global__ __launch_bounds__(1024) void k_reduce(
    const float* __restrict__ rowloss, float* __restrict__ out)
{
    __shared__ float sm[16];
    int tid = threadIdx.x;
    float s = 0.f;
    #pragma unroll
    for (int i = 0; i < M_ROWS / 1024; ++i) s += rowloss[i * 1024 + tid];
    #pragma unroll
    for (int o = 32; o >= 1; o >>= 1) s += __shfl_xor(s, o);
    if ((tid & 63) == 0) sm[tid >> 6] = s;
    __syncthreads();
    if (tid == 0) {
        float tot = 0.f;
        #pragma unroll
        for (int w = 0; w < 16; ++w) tot += sm[w];
        out[0] = tot * (1.0f / (float)M_ROWS);
    }
}

// ---------------------------------------------------------------------------
extern "C" void kernel_launch(void* const* d_in, const int* in_sizes, int n_in,
                              void* d_out, int out_size, void* d_ws, size_t ws_size,
                              hipStream_t stream)
{
    const float* zi = (const float*)d_in[0];
    const float* zj = (const float*)d_in[1];

    float* rspart  = (float*)d_ws;                                  // 8*8192 f32 = 256KB
    float* rowloss = (float*)((char*)d_ws + 262144);                // 8192 f32
    __hip_bfloat16* zb = (__hip_bfloat16*)((char*)d_ws + 262144 + 32768); // 2MB

    k_normalize<<<dim3(M_ROWS * 64 / 256), 256, 0, stream>>>(zi, zj, zb);
    k_simsum<<<dim3(NCHUNK, 64), dim3(256), 0, stream>>>(zb, rspart);
    k_rowloss<<<dim3(M_ROWS * 64 / 256), 256, 0, stream>>>(zb, rspart, rowloss);
    k_reduce<<<dim3(1), dim3(1024), 0, stream>>>(rowloss, (float*)d_out);
}